// Round 1
// baseline (168.897 us; speedup 1.0000x reference)
//
#include <hip/hip_runtime.h>
#include <cstdint>
#include <cstddef>

#define BB 16
#define NTOT 1048576
#define SS 32
#define SEG 32768
#define DIM 256
#define NSEG_ACT 30   // segments 2..31
#define VW 512        // verifier bitmap words (16384 bits)

// workspace layout (bytes)
#define OFF_HX 0u
#define OFF_HY (512u*1024u)
#define OFF_AX (1024u*1024u)
#define OFF_AY (OFF_AX + 4096u)
#define OFF_PR (OFF_AY + 4096u)
#define OFF_BM (OFF_PR + 4096u)
// OFF_BM + 16*30*512*4 = ~2.0 MB total

__device__ __forceinline__ int clamp255(int v) {
    return v < 0 ? 0 : (v > 255 ? 255 : v);
}

// ---------------- K1: per-(batch,chunk) histograms of xs and ys ----------------
__global__ __launch_bounds__(256) void k_hist(const int* __restrict__ xs,
                                              const int* __restrict__ ys,
                                              uint32_t* __restrict__ histX,
                                              uint32_t* __restrict__ histY) {
    int blk = blockIdx.x;          // 0..511
    int b = blk >> 5, s = blk & 31;
    __shared__ uint32_t hx[256];
    __shared__ uint32_t hy[256];
    int t = threadIdx.x;
    hx[t] = 0u; hy[t] = 0u;
    __syncthreads();
    const int4* x4 = (const int4*)(xs + (size_t)b * NTOT + (size_t)s * SEG);
    const int4* y4 = (const int4*)(ys + (size_t)b * NTOT + (size_t)s * SEG);
    for (int i = 0; i < 32; ++i) {
        int4 xv = x4[i * 256 + t];
        int4 yv = y4[i * 256 + t];
        atomicAdd(&hx[xv.x], 1u); atomicAdd(&hy[yv.x], 1u);
        atomicAdd(&hx[xv.y], 1u); atomicAdd(&hy[yv.y], 1u);
        atomicAdd(&hx[xv.z], 1u); atomicAdd(&hy[yv.z], 1u);
        atomicAdd(&hx[xv.w], 1u); atomicAdd(&hy[yv.w], 1u);
    }
    __syncthreads();
    histX[(size_t)(b * SS + s) * 256 + t] = hx[t];
    histY[(size_t)(b * SS + s) * 256 + t] = hy[t];
}

// ---------------- K2: stats -> clip -> blur -> centroid -> aligned shifts ------
__global__ __launch_bounds__(256) void k_shifts(const uint32_t* __restrict__ histX,
                                                const uint32_t* __restrict__ histY,
                                                const float* __restrict__ blurk,
                                                int* __restrict__ alignedX,
                                                int* __restrict__ alignedY) {
    int blk = blockIdx.x;          // 0..31 : b*2 + axis
    int b = blk >> 1, axis = blk & 1;
    const uint32_t* hist = (axis == 0 ? histX : histY) + (size_t)b * SS * DIM;
    int* out = (axis == 0 ? alignedX : alignedY) + b * SS;

    __shared__ float vals[SS][DIM];
    __shared__ double red[256];
    __shared__ float mrow[SS];
    __shared__ float thr_s;
    int t = threadIdx.x;

    // load + accumulate squared deviations (mean is exactly 128: hist sums to 2^20)
    double ss = 0.0;
    for (int s = 0; s < SS; ++s) {
        float v = (float)hist[s * DIM + t];
        vals[s][t] = v;
        double d = (double)v - 128.0;
        ss += d * d;
    }
    red[t] = ss;
    __syncthreads();
    for (int off = 128; off > 0; off >>= 1) {
        if (t < off) red[t] += red[t + off];
        __syncthreads();
    }
    if (t == 0) {
        float s2 = (float)red[0];          // exact integer (< 2^24 in practice)
        float var = s2 / 8191.0f;          // ddof=1
        float sd = sqrtf(var);
        thr_s = 128.0f + 3.0f * sd;
    }
    __syncthreads();
    float thr = thr_s;
    for (int s = 0; s < SS; ++s)
        vals[s][t] = fminf(vals[s][t], thr);   // values are >= 0 already
    __syncthreads();

    // blur kernel (3x3) — symmetric, use actual values
    float k00 = blurk[0], k01 = blurk[1], k02 = blurk[2];
    float k10 = blurk[3], k11 = blurk[4], k12 = blurk[5];
    float k20 = blurk[6], k21 = blurk[7], k22 = blurk[8];

    for (int s = 0; s < SS; ++s) {
        // blurred[s][t] = 3x3 cross-correlation with zero padding
        float bsum = 0.0f;
        int cm = t - 1, cp = t + 1;
        bool cml = (cm >= 0), cpl = (cp < DIM);
        // row s-1
        if (s - 1 >= 0) {
            if (cml) bsum += k00 * vals[s - 1][cm];
            bsum += k01 * vals[s - 1][t];
            if (cpl) bsum += k02 * vals[s - 1][cp];
        }
        // row s
        if (cml) bsum += k10 * vals[s][cm];
        bsum += k11 * vals[s][t];
        if (cpl) bsum += k12 * vals[s][cp];
        // row s+1
        if (s + 1 < SS) {
            if (cml) bsum += k20 * vals[s + 1][cm];
            bsum += k21 * vals[s + 1][t];
            if (cpl) bsum += k22 * vals[s + 1][cp];
        }
        __syncthreads();          // previous red[] consumption done
        red[t] = (double)bsum * (double)t;
        __syncthreads();
        for (int off = 128; off > 0; off >>= 1) {
            if (t < off) red[t] += red[t + off];
            __syncthreads();
        }
        if (t == 0) mrow[s] = (float)(red[0] / 32768.0);
        __syncthreads();
    }

    if (t < SS) {
        float start = mrow[2];                    // START = 2
        float a = mrow[t] - start;
        float c = 128.0f - start;                 // dimlen//2 - start
        out[t] = (int)rintf(a - c);               // round half-to-even
    }
}

// ---------------- K3: per-(batch,segment>=2) verifier bitmaps ------------------
__global__ __launch_bounds__(256) void k_bitmap(const int* __restrict__ xs,
                                                const int* __restrict__ ys,
                                                const int* __restrict__ aX,
                                                const int* __restrict__ aY,
                                                uint32_t* __restrict__ bitmaps) {
    int blk = blockIdx.x;                 // 0..479
    int b = blk / NSEG_ACT, si = blk % NSEG_ACT, s = si + 2;
    int shx = aX[b * SS + s];
    int shy = aY[b * SS + s];
    __shared__ uint32_t bm[VW];
    int t = threadIdx.x;
    bm[t] = 0u; bm[t + 256] = 0u;
    __syncthreads();
    const int4* x4 = (const int4*)(xs + (size_t)b * NTOT + (size_t)s * SEG);
    const int4* y4 = (const int4*)(ys + (size_t)b * NTOT + (size_t)s * SEG);
    for (int i = 0; i < 32; ++i) {
        int4 xv = x4[i * 256 + t];
        int4 yv = y4[i * 256 + t];
#define DOV(xc, yc) { int xf = clamp255((xc) - shx); int yf = clamp255((yc) - shy); \
                      int iv = (xf >> 1) + ((yf >> 1) << 7); \
                      atomicOr(&bm[iv >> 5], 1u << (iv & 31)); }
        DOV(xv.x, yv.x) DOV(xv.y, yv.y) DOV(xv.z, yv.z) DOV(xv.w, yv.w)
#undef DOV
    }
    __syncthreads();
    uint32_t* outp = bitmaps + (size_t)(b * NSEG_ACT + si) * VW;
    outp[t] = bm[t];
    outp[t + 256] = bm[t + 256];
}

// ---------------- K4: sequential verifier scan -> proceed flags ----------------
__global__ __launch_bounds__(256) void k_scan(const uint32_t* __restrict__ bitmaps,
                                              int* __restrict__ proceed) {
    int b = blockIdx.x;                   // 0..15
    int t = threadIdx.x;
    __shared__ uint32_t ver[VW];
    __shared__ int wred[4];
    __shared__ int sh_flag;
    __shared__ int sh_total;
    const uint32_t* bmb = bitmaps + (size_t)b * NSEG_ACT * VW;

    if (t < SS) proceed[b * SS + t] = 0;
    ver[t] = bmb[t];
    ver[t + 256] = bmb[t + 256];
    __syncthreads();

    int wid = t >> 6, lane = t & 63;
    {
        int c = __popc(ver[t]) + __popc(ver[t + 256]);
        for (int o = 32; o > 0; o >>= 1) c += __shfl_down(c, o, 64);
        if (lane == 0) wred[wid] = c;
        __syncthreads();
        if (t == 0) {
            sh_total = wred[0] + wred[1] + wred[2] + wred[3];
            proceed[b * SS + 2] = 1;       // START segment always counted
        }
        __syncthreads();
    }

    for (int s = 3; s < SS; ++s) {
        const uint32_t* bm = bmb + (size_t)(s - 2) * VW;
        uint32_t w0 = bm[t], w1 = bm[t + 256];
        int c = __popc(w0 & ~ver[t]) + __popc(w1 & ~ver[t + 256]);
        for (int o = 32; o > 0; o >>= 1) c += __shfl_down(c, o, 64);
        if (lane == 0) wred[wid] = c;
        __syncthreads();
        if (t == 0) {
            int newly = wred[0] + wred[1] + wred[2] + wred[3];
            int total = sh_total + newly;
            float ratio = (float)newly / (float)total;
            int f = (ratio >= 0.01f) ? 1 : 0;
            sh_flag = f;
            if (f) {
                sh_total = total;
                proceed[b * SS + s] = 1;
            }
        }
        __syncthreads();
        if (!sh_flag) break;              // uniform: once inactive, always inactive
        ver[t] |= w0;
        ver[t + 256] |= w1;
        __syncthreads();
    }
}

// ---------------- K5: accumulate containers for proceeding segments ------------
__global__ __launch_bounds__(256) void k_accum(const int* __restrict__ xs,
                                               const int* __restrict__ ys,
                                               const int* __restrict__ aX,
                                               const int* __restrict__ aY,
                                               const int* __restrict__ proceed,
                                               float* __restrict__ out) {
    int blk = blockIdx.x;                 // 0..479
    int b = blk / NSEG_ACT, si = blk % NSEG_ACT, s = si + 2;
    if (!proceed[b * SS + s]) return;
    int shx = aX[b * SS + s];
    int shy = aY[b * SS + s];
    float* ob = out + (size_t)b * 65536;
    int t = threadIdx.x;
    const int4* x4 = (const int4*)(xs + (size_t)b * NTOT + (size_t)s * SEG);
    const int4* y4 = (const int4*)(ys + (size_t)b * NTOT + (size_t)s * SEG);
    for (int i = 0; i < 32; ++i) {
        int4 xv = x4[i * 256 + t];
        int4 yv = y4[i * 256 + t];
#define DOC(xc, yc) { int xf = clamp255((xc) - shx); int yf = clamp255((yc) - shy); \
                      atomicAdd(&ob[xf + (yf << 8)], 1.0f); }
        DOC(xv.x, yv.x) DOC(xv.y, yv.y) DOC(xv.z, yv.z) DOC(xv.w, yv.w)
#undef DOC
    }
}

extern "C" void kernel_launch(void* const* d_in, const int* in_sizes, int n_in,
                              void* d_out, int out_size, void* d_ws, size_t ws_size,
                              hipStream_t stream) {
    const int* xs = (const int*)d_in[0];
    const int* ys = (const int*)d_in[1];
    const float* blurk = (const float*)d_in[2];
    float* out = (float*)d_out;

    uint8_t* ws = (uint8_t*)d_ws;
    uint32_t* histX = (uint32_t*)(ws + OFF_HX);
    uint32_t* histY = (uint32_t*)(ws + OFF_HY);
    int* aX = (int*)(ws + OFF_AX);
    int* aY = (int*)(ws + OFF_AY);
    int* proceed = (int*)(ws + OFF_PR);
    uint32_t* bitmaps = (uint32_t*)(ws + OFF_BM);

    hipMemsetAsync(d_out, 0, (size_t)out_size * sizeof(float), stream);

    k_hist<<<BB * SS, 256, 0, stream>>>(xs, ys, histX, histY);
    k_shifts<<<BB * 2, 256, 0, stream>>>(histX, histY, blurk, aX, aY);
    k_bitmap<<<BB * NSEG_ACT, 256, 0, stream>>>(xs, ys, aX, aY, bitmaps);
    k_scan<<<BB, 256, 0, stream>>>(bitmaps, proceed);
    k_accum<<<BB * NSEG_ACT, 256, 0, stream>>>(xs, ys, aX, aY, proceed, out);
}

// Round 2
// 104.461 us; speedup vs baseline: 1.6168x; 1.6168x over previous
//
#include <hip/hip_runtime.h>
#include <cstdint>
#include <cstddef>

#define BB 16
#define NTOT 1048576
#define SS 32
#define SEG 32768
#define DIM 256
#define NSEG_ACT 30   // segments 2..31
#define VW 512        // verifier bitmap words (16384 bits)

// workspace layout (bytes)
#define OFF_HX 0u
#define OFF_HY (512u*1024u)
#define OFF_AX (1024u*1024u)
#define OFF_AY (OFF_AX + 4096u)
#define OFF_PR (OFF_AY + 4096u)
#define OFF_BM (OFF_PR + 4096u)
// OFF_BM + 16*30*512*4 = ~2.0 MB total

__device__ __forceinline__ int clamp255(int v) {
    return v < 0 ? 0 : (v > 255 ? 255 : v);
}

// ---------------- K1: per-(batch,chunk) histograms of xs and ys ----------------
__global__ __launch_bounds__(256) void k_hist(const int* __restrict__ xs,
                                              const int* __restrict__ ys,
                                              uint32_t* __restrict__ histX,
                                              uint32_t* __restrict__ histY) {
    int blk = blockIdx.x;          // 0..511
    int b = blk >> 5, s = blk & 31;
    __shared__ uint32_t hx[256];
    __shared__ uint32_t hy[256];
    int t = threadIdx.x;
    hx[t] = 0u; hy[t] = 0u;
    __syncthreads();
    const int4* x4 = (const int4*)(xs + (size_t)b * NTOT + (size_t)s * SEG);
    const int4* y4 = (const int4*)(ys + (size_t)b * NTOT + (size_t)s * SEG);
    for (int i = 0; i < 32; ++i) {
        int4 xv = x4[i * 256 + t];
        int4 yv = y4[i * 256 + t];
        atomicAdd(&hx[xv.x], 1u); atomicAdd(&hy[yv.x], 1u);
        atomicAdd(&hx[xv.y], 1u); atomicAdd(&hy[yv.y], 1u);
        atomicAdd(&hx[xv.z], 1u); atomicAdd(&hy[yv.z], 1u);
        atomicAdd(&hx[xv.w], 1u); atomicAdd(&hy[yv.w], 1u);
    }
    __syncthreads();
    histX[(size_t)(b * SS + s) * 256 + t] = hx[t];
    histY[(size_t)(b * SS + s) * 256 + t] = hy[t];
}

// ---------------- K2: stats -> clip -> blur -> centroid -> aligned shifts ------
__global__ __launch_bounds__(256) void k_shifts(const uint32_t* __restrict__ histX,
                                                const uint32_t* __restrict__ histY,
                                                const float* __restrict__ blurk,
                                                int* __restrict__ alignedX,
                                                int* __restrict__ alignedY) {
    int blk = blockIdx.x;          // 0..31 : b*2 + axis
    int b = blk >> 1, axis = blk & 1;
    const uint32_t* hist = (axis == 0 ? histX : histY) + (size_t)b * SS * DIM;
    int* out = (axis == 0 ? alignedX : alignedY) + b * SS;

    __shared__ float vals[SS][DIM];
    __shared__ double red[256];
    __shared__ float mrow[SS];
    __shared__ float thr_s;
    int t = threadIdx.x;

    // load + accumulate squared deviations (mean is exactly 128: hist sums to 2^20)
    double ss = 0.0;
    for (int s = 0; s < SS; ++s) {
        float v = (float)hist[s * DIM + t];
        vals[s][t] = v;
        double d = (double)v - 128.0;
        ss += d * d;
    }
    red[t] = ss;
    __syncthreads();
    for (int off = 128; off > 0; off >>= 1) {
        if (t < off) red[t] += red[t + off];
        __syncthreads();
    }
    if (t == 0) {
        float s2 = (float)red[0];          // exact integer (< 2^24 in practice)
        float var = s2 / 8191.0f;          // ddof=1
        float sd = sqrtf(var);
        thr_s = 128.0f + 3.0f * sd;
    }
    __syncthreads();
    float thr = thr_s;
    for (int s = 0; s < SS; ++s)
        vals[s][t] = fminf(vals[s][t], thr);   // values are >= 0 already
    __syncthreads();

    // blur kernel (3x3) — symmetric, use actual values
    float k00 = blurk[0], k01 = blurk[1], k02 = blurk[2];
    float k10 = blurk[3], k11 = blurk[4], k12 = blurk[5];
    float k20 = blurk[6], k21 = blurk[7], k22 = blurk[8];

    for (int s = 0; s < SS; ++s) {
        // blurred[s][t] = 3x3 cross-correlation with zero padding
        float bsum = 0.0f;
        int cm = t - 1, cp = t + 1;
        bool cml = (cm >= 0), cpl = (cp < DIM);
        // row s-1
        if (s - 1 >= 0) {
            if (cml) bsum += k00 * vals[s - 1][cm];
            bsum += k01 * vals[s - 1][t];
            if (cpl) bsum += k02 * vals[s - 1][cp];
        }
        // row s
        if (cml) bsum += k10 * vals[s][cm];
        bsum += k11 * vals[s][t];
        if (cpl) bsum += k12 * vals[s][cp];
        // row s+1
        if (s + 1 < SS) {
            if (cml) bsum += k20 * vals[s + 1][cm];
            bsum += k21 * vals[s + 1][t];
            if (cpl) bsum += k22 * vals[s + 1][cp];
        }
        __syncthreads();          // previous red[] consumption done
        red[t] = (double)bsum * (double)t;
        __syncthreads();
        for (int off = 128; off > 0; off >>= 1) {
            if (t < off) red[t] += red[t + off];
            __syncthreads();
        }
        if (t == 0) mrow[s] = (float)(red[0] / 32768.0);
        __syncthreads();
    }

    if (t < SS) {
        float start = mrow[2];                    // START = 2
        float a = mrow[t] - start;
        float c = 128.0f - start;                 // dimlen//2 - start
        out[t] = (int)rintf(a - c);               // round half-to-even
    }
}

// ---------------- K3: per-(batch,segment>=2) verifier bitmaps ------------------
__global__ __launch_bounds__(256) void k_bitmap(const int* __restrict__ xs,
                                                const int* __restrict__ ys,
                                                const int* __restrict__ aX,
                                                const int* __restrict__ aY,
                                                uint32_t* __restrict__ bitmaps) {
    int blk = blockIdx.x;                 // 0..479
    int b = blk / NSEG_ACT, si = blk % NSEG_ACT, s = si + 2;
    int shx = aX[b * SS + s];
    int shy = aY[b * SS + s];
    __shared__ uint32_t bm[VW];
    int t = threadIdx.x;
    bm[t] = 0u; bm[t + 256] = 0u;
    __syncthreads();
    const int4* x4 = (const int4*)(xs + (size_t)b * NTOT + (size_t)s * SEG);
    const int4* y4 = (const int4*)(ys + (size_t)b * NTOT + (size_t)s * SEG);
    for (int i = 0; i < 32; ++i) {
        int4 xv = x4[i * 256 + t];
        int4 yv = y4[i * 256 + t];
#define DOV(xc, yc) { int xf = clamp255((xc) - shx); int yf = clamp255((yc) - shy); \
                      int iv = (xf >> 1) + ((yf >> 1) << 7); \
                      atomicOr(&bm[iv >> 5], 1u << (iv & 31)); }
        DOV(xv.x, yv.x) DOV(xv.y, yv.y) DOV(xv.z, yv.z) DOV(xv.w, yv.w)
#undef DOV
    }
    __syncthreads();
    uint32_t* outp = bitmaps + (size_t)(b * NSEG_ACT + si) * VW;
    outp[t] = bm[t];
    outp[t + 256] = bm[t + 256];
}

// ---------------- K4: sequential verifier scan -> proceed flags ----------------
__global__ __launch_bounds__(256) void k_scan(const uint32_t* __restrict__ bitmaps,
                                              int* __restrict__ proceed) {
    int b = blockIdx.x;                   // 0..15
    int t = threadIdx.x;
    __shared__ uint32_t ver[VW];
    __shared__ int wred[4];
    __shared__ int sh_flag;
    __shared__ int sh_total;
    const uint32_t* bmb = bitmaps + (size_t)b * NSEG_ACT * VW;

    if (t < SS) proceed[b * SS + t] = 0;
    ver[t] = bmb[t];
    ver[t + 256] = bmb[t + 256];
    __syncthreads();

    int wid = t >> 6, lane = t & 63;
    {
        int c = __popc(ver[t]) + __popc(ver[t + 256]);
        for (int o = 32; o > 0; o >>= 1) c += __shfl_down(c, o, 64);
        if (lane == 0) wred[wid] = c;
        __syncthreads();
        if (t == 0) {
            sh_total = wred[0] + wred[1] + wred[2] + wred[3];
            proceed[b * SS + 2] = 1;       // START segment always counted
        }
        __syncthreads();
    }

    for (int s = 3; s < SS; ++s) {
        const uint32_t* bm = bmb + (size_t)(s - 2) * VW;
        uint32_t w0 = bm[t], w1 = bm[t + 256];
        int c = __popc(w0 & ~ver[t]) + __popc(w1 & ~ver[t + 256]);
        for (int o = 32; o > 0; o >>= 1) c += __shfl_down(c, o, 64);
        if (lane == 0) wred[wid] = c;
        __syncthreads();
        if (t == 0) {
            int newly = wred[0] + wred[1] + wred[2] + wred[3];
            int total = sh_total + newly;
            float ratio = (float)newly / (float)total;
            int f = (ratio >= 0.01f) ? 1 : 0;
            sh_flag = f;
            if (f) {
                sh_total = total;
                proceed[b * SS + s] = 1;
            }
        }
        __syncthreads();
        if (!sh_flag) break;              // uniform: once inactive, always inactive
        ver[t] |= w0;
        ver[t + 256] |= w1;
        __syncthreads();
    }
}

// ---------------- K5: per-batch-half LDS accumulation (no global atomics) ------
// 2 blocks per batch; each owns the y-half [half*128, half*128+128) of the
// output image. Counts packed u16 x2 per u32 word in 64 KB LDS; max per-cell
// count over <=30 segs with small shifts is << 65535, so no carry into the
// upper half. Final image written with plain coalesced stores (covers ALL
// cells -> no d_out memset needed).
__global__ __launch_bounds__(1024) void k_accum2(const int* __restrict__ xs,
                                                 const int* __restrict__ ys,
                                                 const int* __restrict__ aX,
                                                 const int* __restrict__ aY,
                                                 const int* __restrict__ proceed,
                                                 float* __restrict__ out) {
    int b = blockIdx.x >> 1, half = blockIdx.x & 1;   // 32 blocks
    __shared__ uint32_t acc[16384];                   // 32768 u16 cells
    int t = threadIdx.x;
    for (int i = t; i < 16384; i += 1024) acc[i] = 0u;
    __syncthreads();
    int ybase = half << 7;
    for (int s = 2; s < SS; ++s) {
        if (!proceed[b * SS + s]) continue;
        int shx = aX[b * SS + s];
        int shy = aY[b * SS + s];
        const int4* x4 = (const int4*)(xs + (size_t)b * NTOT + (size_t)s * SEG);
        const int4* y4 = (const int4*)(ys + (size_t)b * NTOT + (size_t)s * SEG);
        for (int i = 0; i < 8; ++i) {
            int4 xv = x4[i * 1024 + t];
            int4 yv = y4[i * 1024 + t];
#define DOC(xc, yc) { int xf = clamp255((xc) - shx); int yf = clamp255((yc) - shy); \
                      if ((yf >> 7) == half) { \
                          int cell = xf + ((yf - ybase) << 8); \
                          atomicAdd(&acc[cell >> 1], 1u << ((cell & 1) << 4)); } }
            DOC(xv.x, yv.x) DOC(xv.y, yv.y) DOC(xv.z, yv.z) DOC(xv.w, yv.w)
#undef DOC
        }
    }
    __syncthreads();
    float2* ob = (float2*)(out + (size_t)b * 65536 + ((size_t)half << 15));
    for (int i = t; i < 16384; i += 1024) {
        uint32_t w = acc[i];
        ob[i] = make_float2((float)(w & 0xFFFFu), (float)(w >> 16));
    }
}

extern "C" void kernel_launch(void* const* d_in, const int* in_sizes, int n_in,
                              void* d_out, int out_size, void* d_ws, size_t ws_size,
                              hipStream_t stream) {
    const int* xs = (const int*)d_in[0];
    const int* ys = (const int*)d_in[1];
    const float* blurk = (const float*)d_in[2];
    float* out = (float*)d_out;

    uint8_t* ws = (uint8_t*)d_ws;
    uint32_t* histX = (uint32_t*)(ws + OFF_HX);
    uint32_t* histY = (uint32_t*)(ws + OFF_HY);
    int* aX = (int*)(ws + OFF_AX);
    int* aY = (int*)(ws + OFF_AY);
    int* proceed = (int*)(ws + OFF_PR);
    uint32_t* bitmaps = (uint32_t*)(ws + OFF_BM);

    k_hist<<<BB * SS, 256, 0, stream>>>(xs, ys, histX, histY);
    k_shifts<<<BB * 2, 256, 0, stream>>>(histX, histY, blurk, aX, aY);
    k_bitmap<<<BB * NSEG_ACT, 256, 0, stream>>>(xs, ys, aX, aY, bitmaps);
    k_scan<<<BB, 256, 0, stream>>>(bitmaps, proceed);
    k_accum2<<<BB * 2, 1024, 0, stream>>>(xs, ys, aX, aY, proceed, out);
}

// Round 4
// 103.320 us; speedup vs baseline: 1.6347x; 1.0110x over previous
//
#include <hip/hip_runtime.h>
#include <cstdint>
#include <cstddef>

#define BB 16
#define NTOT 1048576
#define SS 32
#define SEG 32768
#define DIM 256
#define VW 512        // verifier bitmap words (16384 bits)
#define PARTS 4       // partial blocks per (b,seg) bitmap
#define PH 8          // partial blocks per (b,seg) histogram
#define MAXSEG 22     // max segments per scan group (group1: segs 10..31)

// ---------------- workspace layout (bytes), sizes derived explicitly ----------
// bitmaps: BB*MAXSEG*PARTS*VW*4 = 16*22*4*512*4 = 2,883,584 B
// histX  : BB*SS*256*4          = 16*32*256*4   =   524,288 B
// histY  : same                                  =   524,288 B
// hist region [0, 1,048,576) is DEAD after k_shifts; bitmaps [0, 2,883,584)
// alias over it (stream-ordered, disjoint lifetimes).
#define OFF_BM   0u
#define OFF_HX   0u
#define OFF_HY   524288u
#define OFF_AX   2883584u            // BB*SS*4 = 2048 B
#define OFF_AY   2885632u            // 2048 B
#define OFF_PR   2887680u            // 2048 B
#define OFF_ACT  2889728u            // 1024 B
#define OFF_TOT  2890752u            // 1024 B
#define OFF_VER  2891776u            // BB*VW*4 = 32768 B -> end 2,924,544 (~2.9 MB)

__device__ __forceinline__ int clamp255(int v) {
    return v < 0 ? 0 : (v > 255 ? 255 : v);
}

// ---------------- K1: partial histograms, merged via global atomics ------------
// grid = BB*SS*PH blocks; block (b,s,p) histograms elems [p*4096,(p+1)*4096)
__global__ __launch_bounds__(256) void k_hist(const int* __restrict__ xs,
                                              const int* __restrict__ ys,
                                              uint32_t* __restrict__ histX,
                                              uint32_t* __restrict__ histY) {
    int blk = blockIdx.x;
    int p = blk & (PH - 1);
    int s = (blk >> 3) & 31;
    int b = blk >> 8;
    __shared__ uint32_t hx[256];
    __shared__ uint32_t hy[256];
    int t = threadIdx.x;
    hx[t] = 0u; hy[t] = 0u;
    __syncthreads();
    size_t base = (size_t)b * NTOT + (size_t)s * SEG + (size_t)p * 4096;
    const int4* x4 = (const int4*)(xs + base);
    const int4* y4 = (const int4*)(ys + base);
    for (int i = 0; i < 4; ++i) {
        int4 xv = x4[i * 256 + t];
        int4 yv = y4[i * 256 + t];
        atomicAdd(&hx[xv.x], 1u); atomicAdd(&hy[yv.x], 1u);
        atomicAdd(&hx[xv.y], 1u); atomicAdd(&hy[yv.y], 1u);
        atomicAdd(&hx[xv.z], 1u); atomicAdd(&hy[yv.z], 1u);
        atomicAdd(&hx[xv.w], 1u); atomicAdd(&hy[yv.w], 1u);
    }
    __syncthreads();
    atomicAdd(&histX[(size_t)(b * SS + s) * 256 + t], hx[t]);
    atomicAdd(&histY[(size_t)(b * SS + s) * 256 + t], hy[t]);
}

// ---------------- K2: stats -> clip -> blur -> centroid -> aligned shifts ------
__global__ __launch_bounds__(256) void k_shifts(const uint32_t* __restrict__ histX,
                                                const uint32_t* __restrict__ histY,
                                                const float* __restrict__ blurk,
                                                int* __restrict__ alignedX,
                                                int* __restrict__ alignedY) {
    int blk = blockIdx.x;          // 0..31 : b*2 + axis
    int b = blk >> 1, axis = blk & 1;
    const uint32_t* hist = (axis == 0 ? histX : histY) + (size_t)b * SS * DIM;
    int* out = (axis == 0 ? alignedX : alignedY) + b * SS;

    __shared__ float vals[SS][DIM];
    __shared__ double red[256];
    __shared__ float mrow[SS];
    __shared__ float thr_s;
    int t = threadIdx.x;

    double ss = 0.0;
    for (int s = 0; s < SS; ++s) {
        float v = (float)hist[s * DIM + t];
        vals[s][t] = v;
        double d = (double)v - 128.0;
        ss += d * d;
    }
    red[t] = ss;
    __syncthreads();
    for (int off = 128; off > 0; off >>= 1) {
        if (t < off) red[t] += red[t + off];
        __syncthreads();
    }
    if (t == 0) {
        float s2 = (float)red[0];          // exact integer
        float var = s2 / 8191.0f;          // ddof=1
        float sd = sqrtf(var);
        thr_s = 128.0f + 3.0f * sd;
    }
    __syncthreads();
    float thr = thr_s;
    for (int s = 0; s < SS; ++s)
        vals[s][t] = fminf(vals[s][t], thr);
    __syncthreads();

    float k00 = blurk[0], k01 = blurk[1], k02 = blurk[2];
    float k10 = blurk[3], k11 = blurk[4], k12 = blurk[5];
    float k20 = blurk[6], k21 = blurk[7], k22 = blurk[8];

    for (int s = 0; s < SS; ++s) {
        float bsum = 0.0f;
        int cm = t - 1, cp = t + 1;
        bool cml = (cm >= 0), cpl = (cp < DIM);
        if (s - 1 >= 0) {
            if (cml) bsum += k00 * vals[s - 1][cm];
            bsum += k01 * vals[s - 1][t];
            if (cpl) bsum += k02 * vals[s - 1][cp];
        }
        if (cml) bsum += k10 * vals[s][cm];
        bsum += k11 * vals[s][t];
        if (cpl) bsum += k12 * vals[s][cp];
        if (s + 1 < SS) {
            if (cml) bsum += k20 * vals[s + 1][cm];
            bsum += k21 * vals[s + 1][t];
            if (cpl) bsum += k22 * vals[s + 1][cp];
        }
        __syncthreads();
        red[t] = (double)bsum * (double)t;
        __syncthreads();
        for (int off = 128; off > 0; off >>= 1) {
            if (t < off) red[t] += red[t + off];
            __syncthreads();
        }
        if (t == 0) mrow[s] = (float)(red[0] / 32768.0);
        __syncthreads();
    }

    if (t < SS) {
        float start = mrow[2];                    // START = 2
        float a = mrow[t] - start;
        float c = 128.0f - start;                 // dimlen//2 - start
        out[t] = (int)rintf(a - c);               // round half-to-even
    }
}

// ---------------- K3: partial verifier bitmaps for a segment group -------------
// grid = BB * nseg * PARTS; each partial block writes its own VW-word bitmap
// (no atomics, no zeroing needed — all words written unconditionally).
__global__ __launch_bounds__(256) void k_bitmap_g(const int* __restrict__ xs,
                                                  const int* __restrict__ ys,
                                                  const int* __restrict__ aX,
                                                  const int* __restrict__ aY,
                                                  const int* __restrict__ active,
                                                  uint32_t* __restrict__ bmp,
                                                  int first_seg, int nseg,
                                                  int check_active) {
    int blk = blockIdx.x;
    int p = blk % PARTS;
    int sl = (blk / PARTS) % nseg;
    int b = blk / (PARTS * nseg);
    if (check_active && !active[b]) return;
    int s = first_seg + sl;
    int shx = aX[b * SS + s];
    int shy = aY[b * SS + s];
    __shared__ uint32_t bm[VW];
    int t = threadIdx.x;
    bm[t] = 0u; bm[t + 256] = 0u;
    __syncthreads();
    size_t base = (size_t)b * NTOT + (size_t)s * SEG + (size_t)p * (SEG / PARTS);
    const int4* x4 = (const int4*)(xs + base);
    const int4* y4 = (const int4*)(ys + base);
    for (int i = 0; i < 8; ++i) {
        int4 xv = x4[i * 256 + t];
        int4 yv = y4[i * 256 + t];
#define DOV(xc, yc) { int xf = clamp255((xc) - shx); int yf = clamp255((yc) - shy); \
                      int iv = (xf >> 1) + ((yf >> 1) << 7); \
                      atomicOr(&bm[iv >> 5], 1u << (iv & 31)); }
        DOV(xv.x, yv.x) DOV(xv.y, yv.y) DOV(xv.z, yv.z) DOV(xv.w, yv.w)
#undef DOV
    }
    __syncthreads();
    uint32_t* outp = bmp + ((size_t)(b * MAXSEG + sl) * PARTS + p) * VW;
    outp[t] = bm[t];
    outp[t + 256] = bm[t + 256];
}

// ---------------- K4: sequential verifier scan over one group ------------------
__global__ __launch_bounds__(256) void k_scan_g(const uint32_t* __restrict__ bmp,
                                                int* __restrict__ proceed,
                                                uint32_t* __restrict__ ver_state,
                                                int* __restrict__ total_state,
                                                int* __restrict__ active_state,
                                                int first_seg, int nseg, int do_init) {
    int b = blockIdx.x;                   // 0..15
    int t = threadIdx.x;
    __shared__ uint32_t ver[VW];
    __shared__ int wred[4];
    __shared__ int sh_flag;
    __shared__ int sh_total;

    // default proceed=0 for this group's segments
    for (int i = t; i < nseg; i += 256) proceed[b * SS + first_seg + i] = 0;

    int active = do_init ? 1 : active_state[b];
    if (!active) {
        if (t == 0) active_state[b] = 0;
        return;
    }

    const uint32_t* base = bmp + (size_t)b * MAXSEG * PARTS * VW;
    int wid = t >> 6, lane = t & 63;
    int start_local;

    if (do_init) {
        uint32_t w0 = 0, w1 = 0;
        for (int p = 0; p < PARTS; ++p) {
            w0 |= base[(size_t)(0 * PARTS + p) * VW + t];
            w1 |= base[(size_t)(0 * PARTS + p) * VW + t + 256];
        }
        ver[t] = w0; ver[t + 256] = w1;
        int c = __popc(w0) + __popc(w1);
        for (int o = 32; o > 0; o >>= 1) c += __shfl_down(c, o, 64);
        if (lane == 0) wred[wid] = c;
        __syncthreads();
        if (t == 0) {
            sh_total = wred[0] + wred[1] + wred[2] + wred[3];
            proceed[b * SS + first_seg] = 1;   // START segment
        }
        start_local = 1;
    } else {
        ver[t] = ver_state[(size_t)b * VW + t];
        ver[t + 256] = ver_state[(size_t)b * VW + t + 256];
        if (t == 0) sh_total = total_state[b];
        start_local = 0;
    }
    __syncthreads();

    for (int sl = start_local; sl < nseg; ++sl) {
        uint32_t w0 = 0, w1 = 0;
        for (int p = 0; p < PARTS; ++p) {
            w0 |= base[(size_t)(sl * PARTS + p) * VW + t];
            w1 |= base[(size_t)(sl * PARTS + p) * VW + t + 256];
        }
        int c = __popc(w0 & ~ver[t]) + __popc(w1 & ~ver[t + 256]);
        for (int o = 32; o > 0; o >>= 1) c += __shfl_down(c, o, 64);
        if (lane == 0) wred[wid] = c;
        __syncthreads();
        if (t == 0) {
            int newly = wred[0] + wred[1] + wred[2] + wred[3];
            int total = sh_total + newly;
            float ratio = (float)newly / (float)total;
            int f = (ratio >= 0.01f) ? 1 : 0;
            sh_flag = f;
            if (f) {
                sh_total = total;
                proceed[b * SS + first_seg + sl] = 1;
            }
        }
        __syncthreads();
        if (!sh_flag) { active = 0; break; }
        ver[t] |= w0;
        ver[t + 256] |= w1;
        __syncthreads();
    }

    // save state for next group
    ver_state[(size_t)b * VW + t] = ver[t];
    ver_state[(size_t)b * VW + t + 256] = ver[t + 256];
    if (t == 0) {
        total_state[b] = sh_total;
        active_state[b] = active;
    }
}

// ---------------- K5: per-batch-quadrant LDS accumulation ----------------------
// 4 blocks per batch; each owns y-rows [quad*64, quad*64+64). Packed u16 counts
// in 32 KB LDS; plain coalesced stores cover all cells (no d_out memset).
__global__ __launch_bounds__(1024) void k_accum2(const int* __restrict__ xs,
                                                 const int* __restrict__ ys,
                                                 const int* __restrict__ aX,
                                                 const int* __restrict__ aY,
                                                 const int* __restrict__ proceed,
                                                 float* __restrict__ out) {
    int b = blockIdx.x >> 2, quad = blockIdx.x & 3;   // 64 blocks
    __shared__ uint32_t acc[8192];                    // 16384 u16 cells (64x256)
    int t = threadIdx.x;
    for (int i = t; i < 8192; i += 1024) acc[i] = 0u;
    __syncthreads();
    int ybase = quad << 6;
    for (int s = 2; s < SS; ++s) {
        if (!proceed[b * SS + s]) continue;
        int shx = aX[b * SS + s];
        int shy = aY[b * SS + s];
        const int4* x4 = (const int4*)(xs + (size_t)b * NTOT + (size_t)s * SEG);
        const int4* y4 = (const int4*)(ys + (size_t)b * NTOT + (size_t)s * SEG);
        for (int i = 0; i < 8; ++i) {
            int4 xv = x4[i * 1024 + t];
            int4 yv = y4[i * 1024 + t];
#define DOC(xc, yc) { int xf = clamp255((xc) - shx); int yf = clamp255((yc) - shy); \
                      if ((yf >> 6) == quad) { \
                          int cell = xf + ((yf - ybase) << 8); \
                          atomicAdd(&acc[cell >> 1], 1u << ((cell & 1) << 4)); } }
            DOC(xv.x, yv.x) DOC(xv.y, yv.y) DOC(xv.z, yv.z) DOC(xv.w, yv.w)
#undef DOC
        }
    }
    __syncthreads();
    float2* ob = (float2*)(out + (size_t)b * 65536 + ((size_t)quad << 14));
    for (int i = t; i < 8192; i += 1024) {
        uint32_t w = acc[i];
        ob[i] = make_float2((float)(w & 0xFFFFu), (float)(w >> 16));
    }
}

extern "C" void kernel_launch(void* const* d_in, const int* in_sizes, int n_in,
                              void* d_out, int out_size, void* d_ws, size_t ws_size,
                              hipStream_t stream) {
    const int* xs = (const int*)d_in[0];
    const int* ys = (const int*)d_in[1];
    const float* blurk = (const float*)d_in[2];
    float* out = (float*)d_out;

    uint8_t* ws = (uint8_t*)d_ws;
    uint32_t* histX = (uint32_t*)(ws + OFF_HX);
    uint32_t* histY = (uint32_t*)(ws + OFF_HY);
    int* aX = (int*)(ws + OFF_AX);
    int* aY = (int*)(ws + OFF_AY);
    int* proceed = (int*)(ws + OFF_PR);
    int* active = (int*)(ws + OFF_ACT);
    int* total = (int*)(ws + OFF_TOT);
    uint32_t* ver = (uint32_t*)(ws + OFF_VER);
    uint32_t* bitmaps = (uint32_t*)(ws + OFF_BM);

    hipMemsetAsync(ws + OFF_HX, 0, 1048576, stream);   // zero hist X+Y (1 MB)

    k_hist<<<BB * SS * PH, 256, 0, stream>>>(xs, ys, histX, histY);
    k_shifts<<<BB * 2, 256, 0, stream>>>(histX, histY, blurk, aX, aY);

    // group 0: segments 2..9 (init; no active check). Bitmaps alias dead hists.
    k_bitmap_g<<<BB * 8 * PARTS, 256, 0, stream>>>(xs, ys, aX, aY, active,
                                                   bitmaps, 2, 8, 0);
    k_scan_g<<<BB, 256, 0, stream>>>(bitmaps, proceed, ver, total, active, 2, 8, 1);

    // group 1: segments 10..31 (expected no-op: blocks exit on inactive batch)
    k_bitmap_g<<<BB * MAXSEG * PARTS, 256, 0, stream>>>(xs, ys, aX, aY, active,
                                                        bitmaps, 10, MAXSEG, 1);
    k_scan_g<<<BB, 256, 0, stream>>>(bitmaps, proceed, ver, total, active, 10, MAXSEG, 0);

    k_accum2<<<BB * 4, 1024, 0, stream>>>(xs, ys, aX, aY, proceed, out);
}

// Round 5
// 102.731 us; speedup vs baseline: 1.6441x; 1.0057x over previous
//
#include <hip/hip_runtime.h>
#include <cstdint>
#include <cstddef>

#define BB 16
#define NTOT 1048576
#define SS 32
#define SEG 32768
#define DIM 256
#define VW 512        // verifier bitmap words (16384 bits)
#define PARTS 4       // partial blocks per (b,seg) bitmap
#define PH 8          // partial blocks per (b,seg) histogram
#define MAXSEG 22     // max segments per scan group (group1: segs 10..31)

// ---------------- workspace layout (bytes), sizes derived explicitly ----------
// bitmaps: BB*MAXSEG*PARTS*VW*4 = 16*22*4*512*4 = 2,883,584 B
// histX  : BB*SS*256*4          = 16*32*256*4   =   524,288 B
// histY  : same                                  =   524,288 B
// hist region [0, 1,048,576) is DEAD after k_shifts; bitmaps [0, 2,883,584)
// alias over it (stream-ordered, disjoint lifetimes).
#define OFF_BM   0u
#define OFF_HX   0u
#define OFF_HY   524288u
#define OFF_AX   2883584u            // BB*SS*4 = 2048 B
#define OFF_AY   2885632u            // 2048 B
#define OFF_PR   2887680u            // 2048 B
#define OFF_ACT  2889728u            // 1024 B
#define OFF_TOT  2890752u            // 1024 B
#define OFF_VER  2891776u            // BB*VW*4 = 32768 B -> end 2,924,544 (~2.9 MB)

__device__ __forceinline__ int clamp255(int v) {
    return v < 0 ? 0 : (v > 255 ? 255 : v);
}

// ---------------- K1: per-WARP privatized histograms, merged via global atomics
// grid = BB*SS*PH blocks; block (b,s,p) histograms elems [p*4096,(p+1)*4096).
// 4 LDS copies per hist (one per wave) -> zero cross-wave same-address
// contention on ds_add; merge 4 copies at block end.
__global__ __launch_bounds__(256) void k_hist(const int* __restrict__ xs,
                                              const int* __restrict__ ys,
                                              uint32_t* __restrict__ histX,
                                              uint32_t* __restrict__ histY) {
    int blk = blockIdx.x;
    int p = blk & (PH - 1);
    int s = (blk >> 3) & 31;
    int b = blk >> 8;
    __shared__ uint32_t hx[4][256];
    __shared__ uint32_t hy[4][256];
    int t = threadIdx.x;
    int w = t >> 6;                    // wave id 0..3
    hx[0][t] = 0u; hx[1][t] = 0u; hx[2][t] = 0u; hx[3][t] = 0u;
    hy[0][t] = 0u; hy[1][t] = 0u; hy[2][t] = 0u; hy[3][t] = 0u;
    __syncthreads();
    size_t base = (size_t)b * NTOT + (size_t)s * SEG + (size_t)p * 4096;
    const int4* x4 = (const int4*)(xs + base);
    const int4* y4 = (const int4*)(ys + base);
#pragma unroll
    for (int i = 0; i < 4; ++i) {
        int4 xv = x4[i * 256 + t];
        int4 yv = y4[i * 256 + t];
        atomicAdd(&hx[w][xv.x], 1u); atomicAdd(&hy[w][yv.x], 1u);
        atomicAdd(&hx[w][xv.y], 1u); atomicAdd(&hy[w][yv.y], 1u);
        atomicAdd(&hx[w][xv.z], 1u); atomicAdd(&hy[w][yv.z], 1u);
        atomicAdd(&hx[w][xv.w], 1u); atomicAdd(&hy[w][yv.w], 1u);
    }
    __syncthreads();
    uint32_t sx = hx[0][t] + hx[1][t] + hx[2][t] + hx[3][t];
    uint32_t sy = hy[0][t] + hy[1][t] + hy[2][t] + hy[3][t];
    atomicAdd(&histX[(size_t)(b * SS + s) * 256 + t], sx);
    atomicAdd(&histY[(size_t)(b * SS + s) * 256 + t], sy);
}

// ---------------- K2: stats -> clip -> blur -> centroid -> aligned shifts ------
__global__ __launch_bounds__(256) void k_shifts(const uint32_t* __restrict__ histX,
                                                const uint32_t* __restrict__ histY,
                                                const float* __restrict__ blurk,
                                                int* __restrict__ alignedX,
                                                int* __restrict__ alignedY) {
    int blk = blockIdx.x;          // 0..31 : b*2 + axis
    int b = blk >> 1, axis = blk & 1;
    const uint32_t* hist = (axis == 0 ? histX : histY) + (size_t)b * SS * DIM;
    int* out = (axis == 0 ? alignedX : alignedY) + b * SS;

    __shared__ float vals[SS][DIM];
    __shared__ double red[256];
    __shared__ float mrow[SS];
    __shared__ float thr_s;
    int t = threadIdx.x;

    double ss = 0.0;
    for (int s = 0; s < SS; ++s) {
        float v = (float)hist[s * DIM + t];
        vals[s][t] = v;
        double d = (double)v - 128.0;
        ss += d * d;
    }
    red[t] = ss;
    __syncthreads();
    for (int off = 128; off > 0; off >>= 1) {
        if (t < off) red[t] += red[t + off];
        __syncthreads();
    }
    if (t == 0) {
        float s2 = (float)red[0];          // exact integer
        float var = s2 / 8191.0f;          // ddof=1
        float sd = sqrtf(var);
        thr_s = 128.0f + 3.0f * sd;
    }
    __syncthreads();
    float thr = thr_s;
    for (int s = 0; s < SS; ++s)
        vals[s][t] = fminf(vals[s][t], thr);
    __syncthreads();

    float k00 = blurk[0], k01 = blurk[1], k02 = blurk[2];
    float k10 = blurk[3], k11 = blurk[4], k12 = blurk[5];
    float k20 = blurk[6], k21 = blurk[7], k22 = blurk[8];

    for (int s = 0; s < SS; ++s) {
        float bsum = 0.0f;
        int cm = t - 1, cp = t + 1;
        bool cml = (cm >= 0), cpl = (cp < DIM);
        if (s - 1 >= 0) {
            if (cml) bsum += k00 * vals[s - 1][cm];
            bsum += k01 * vals[s - 1][t];
            if (cpl) bsum += k02 * vals[s - 1][cp];
        }
        if (cml) bsum += k10 * vals[s][cm];
        bsum += k11 * vals[s][t];
        if (cpl) bsum += k12 * vals[s][cp];
        if (s + 1 < SS) {
            if (cml) bsum += k20 * vals[s + 1][cm];
            bsum += k21 * vals[s + 1][t];
            if (cpl) bsum += k22 * vals[s + 1][cp];
        }
        __syncthreads();
        red[t] = (double)bsum * (double)t;
        __syncthreads();
        for (int off = 128; off > 0; off >>= 1) {
            if (t < off) red[t] += red[t + off];
            __syncthreads();
        }
        if (t == 0) mrow[s] = (float)(red[0] / 32768.0);
        __syncthreads();
    }

    if (t < SS) {
        float start = mrow[2];                    // START = 2
        float a = mrow[t] - start;
        float c = 128.0f - start;                 // dimlen//2 - start
        out[t] = (int)rintf(a - c);               // round half-to-even
    }
}

// ---------------- K3: partial verifier bitmaps for a segment group -------------
// grid = BB * nseg * PARTS; each partial block writes its own VW-word bitmap
// (no atomics, no zeroing needed — all words written unconditionally).
__global__ __launch_bounds__(256) void k_bitmap_g(const int* __restrict__ xs,
                                                  const int* __restrict__ ys,
                                                  const int* __restrict__ aX,
                                                  const int* __restrict__ aY,
                                                  const int* __restrict__ active,
                                                  uint32_t* __restrict__ bmp,
                                                  int first_seg, int nseg,
                                                  int check_active) {
    int blk = blockIdx.x;
    int p = blk % PARTS;
    int sl = (blk / PARTS) % nseg;
    int b = blk / (PARTS * nseg);
    if (check_active && !active[b]) return;
    int s = first_seg + sl;
    int shx = aX[b * SS + s];
    int shy = aY[b * SS + s];
    __shared__ uint32_t bm[VW];
    int t = threadIdx.x;
    bm[t] = 0u; bm[t + 256] = 0u;
    __syncthreads();
    size_t base = (size_t)b * NTOT + (size_t)s * SEG + (size_t)p * (SEG / PARTS);
    const int4* x4 = (const int4*)(xs + base);
    const int4* y4 = (const int4*)(ys + base);
    for (int i = 0; i < 8; ++i) {
        int4 xv = x4[i * 256 + t];
        int4 yv = y4[i * 256 + t];
#define DOV(xc, yc) { int xf = clamp255((xc) - shx); int yf = clamp255((yc) - shy); \
                      int iv = (xf >> 1) + ((yf >> 1) << 7); \
                      atomicOr(&bm[iv >> 5], 1u << (iv & 31)); }
        DOV(xv.x, yv.x) DOV(xv.y, yv.y) DOV(xv.z, yv.z) DOV(xv.w, yv.w)
#undef DOV
    }
    __syncthreads();
    uint32_t* outp = bmp + ((size_t)(b * MAXSEG + sl) * PARTS + p) * VW;
    outp[t] = bm[t];
    outp[t + 256] = bm[t + 256];
}

// ---------------- K4: sequential verifier scan over one group ------------------
__global__ __launch_bounds__(256) void k_scan_g(const uint32_t* __restrict__ bmp,
                                                int* __restrict__ proceed,
                                                uint32_t* __restrict__ ver_state,
                                                int* __restrict__ total_state,
                                                int* __restrict__ active_state,
                                                int first_seg, int nseg, int do_init) {
    int b = blockIdx.x;                   // 0..15
    int t = threadIdx.x;
    __shared__ uint32_t ver[VW];
    __shared__ int wred[4];
    __shared__ int sh_flag;
    __shared__ int sh_total;

    // default proceed=0 for this group's segments
    for (int i = t; i < nseg; i += 256) proceed[b * SS + first_seg + i] = 0;

    int active = do_init ? 1 : active_state[b];
    if (!active) {
        if (t == 0) active_state[b] = 0;
        return;
    }

    const uint32_t* base = bmp + (size_t)b * MAXSEG * PARTS * VW;
    int wid = t >> 6, lane = t & 63;
    int start_local;

    if (do_init) {
        uint32_t w0 = 0, w1 = 0;
        for (int p = 0; p < PARTS; ++p) {
            w0 |= base[(size_t)(0 * PARTS + p) * VW + t];
            w1 |= base[(size_t)(0 * PARTS + p) * VW + t + 256];
        }
        ver[t] = w0; ver[t + 256] = w1;
        int c = __popc(w0) + __popc(w1);
        for (int o = 32; o > 0; o >>= 1) c += __shfl_down(c, o, 64);
        if (lane == 0) wred[wid] = c;
        __syncthreads();
        if (t == 0) {
            sh_total = wred[0] + wred[1] + wred[2] + wred[3];
            proceed[b * SS + first_seg] = 1;   // START segment
        }
        start_local = 1;
    } else {
        ver[t] = ver_state[(size_t)b * VW + t];
        ver[t + 256] = ver_state[(size_t)b * VW + t + 256];
        if (t == 0) sh_total = total_state[b];
        start_local = 0;
    }
    __syncthreads();

    for (int sl = start_local; sl < nseg; ++sl) {
        uint32_t w0 = 0, w1 = 0;
        for (int p = 0; p < PARTS; ++p) {
            w0 |= base[(size_t)(sl * PARTS + p) * VW + t];
            w1 |= base[(size_t)(sl * PARTS + p) * VW + t + 256];
        }
        int c = __popc(w0 & ~ver[t]) + __popc(w1 & ~ver[t + 256]);
        for (int o = 32; o > 0; o >>= 1) c += __shfl_down(c, o, 64);
        if (lane == 0) wred[wid] = c;
        __syncthreads();
        if (t == 0) {
            int newly = wred[0] + wred[1] + wred[2] + wred[3];
            int total = sh_total + newly;
            float ratio = (float)newly / (float)total;
            int f = (ratio >= 0.01f) ? 1 : 0;
            sh_flag = f;
            if (f) {
                sh_total = total;
                proceed[b * SS + first_seg + sl] = 1;
            }
        }
        __syncthreads();
        if (!sh_flag) { active = 0; break; }
        ver[t] |= w0;
        ver[t + 256] |= w1;
        __syncthreads();
    }

    // save state for next group
    ver_state[(size_t)b * VW + t] = ver[t];
    ver_state[(size_t)b * VW + t + 256] = ver[t + 256];
    if (t == 0) {
        total_state[b] = sh_total;
        active_state[b] = active;
    }
}

// ---------------- K5: per-batch-quadrant LDS accumulation ----------------------
// 4 blocks per batch; each owns y-rows [quad*64, quad*64+64). Packed u16 counts
// in 32 KB LDS; plain coalesced stores cover all cells (no d_out memset).
__global__ __launch_bounds__(1024) void k_accum2(const int* __restrict__ xs,
                                                 const int* __restrict__ ys,
                                                 const int* __restrict__ aX,
                                                 const int* __restrict__ aY,
                                                 const int* __restrict__ proceed,
                                                 float* __restrict__ out) {
    int b = blockIdx.x >> 2, quad = blockIdx.x & 3;   // 64 blocks
    __shared__ uint32_t acc[8192];                    // 16384 u16 cells (64x256)
    int t = threadIdx.x;
    for (int i = t; i < 8192; i += 1024) acc[i] = 0u;
    __syncthreads();
    int ybase = quad << 6;
    for (int s = 2; s < SS; ++s) {
        if (!proceed[b * SS + s]) continue;
        int shx = aX[b * SS + s];
        int shy = aY[b * SS + s];
        const int4* x4 = (const int4*)(xs + (size_t)b * NTOT + (size_t)s * SEG);
        const int4* y4 = (const int4*)(ys + (size_t)b * NTOT + (size_t)s * SEG);
        for (int i = 0; i < 8; ++i) {
            int4 xv = x4[i * 1024 + t];
            int4 yv = y4[i * 1024 + t];
#define DOC(xc, yc) { int xf = clamp255((xc) - shx); int yf = clamp255((yc) - shy); \
                      if ((yf >> 6) == quad) { \
                          int cell = xf + ((yf - ybase) << 8); \
                          atomicAdd(&acc[cell >> 1], 1u << ((cell & 1) << 4)); } }
            DOC(xv.x, yv.x) DOC(xv.y, yv.y) DOC(xv.z, yv.z) DOC(xv.w, yv.w)
#undef DOC
        }
    }
    __syncthreads();
    float2* ob = (float2*)(out + (size_t)b * 65536 + ((size_t)quad << 14));
    for (int i = t; i < 8192; i += 1024) {
        uint32_t w = acc[i];
        ob[i] = make_float2((float)(w & 0xFFFFu), (float)(w >> 16));
    }
}

extern "C" void kernel_launch(void* const* d_in, const int* in_sizes, int n_in,
                              void* d_out, int out_size, void* d_ws, size_t ws_size,
                              hipStream_t stream) {
    const int* xs = (const int*)d_in[0];
    const int* ys = (const int*)d_in[1];
    const float* blurk = (const float*)d_in[2];
    float* out = (float*)d_out;

    uint8_t* ws = (uint8_t*)d_ws;
    uint32_t* histX = (uint32_t*)(ws + OFF_HX);
    uint32_t* histY = (uint32_t*)(ws + OFF_HY);
    int* aX = (int*)(ws + OFF_AX);
    int* aY = (int*)(ws + OFF_AY);
    int* proceed = (int*)(ws + OFF_PR);
    int* active = (int*)(ws + OFF_ACT);
    int* total = (int*)(ws + OFF_TOT);
    uint32_t* ver = (uint32_t*)(ws + OFF_VER);
    uint32_t* bitmaps = (uint32_t*)(ws + OFF_BM);

    hipMemsetAsync(ws + OFF_HX, 0, 1048576, stream);   // zero hist X+Y (1 MB)

    k_hist<<<BB * SS * PH, 256, 0, stream>>>(xs, ys, histX, histY);
    k_shifts<<<BB * 2, 256, 0, stream>>>(histX, histY, blurk, aX, aY);

    // group 0: segments 2..9 (init; no active check). Bitmaps alias dead hists.
    k_bitmap_g<<<BB * 8 * PARTS, 256, 0, stream>>>(xs, ys, aX, aY, active,
                                                   bitmaps, 2, 8, 0);
    k_scan_g<<<BB, 256, 0, stream>>>(bitmaps, proceed, ver, total, active, 2, 8, 1);

    // group 1: segments 10..31 (expected no-op: blocks exit on inactive batch)
    k_bitmap_g<<<BB * MAXSEG * PARTS, 256, 0, stream>>>(xs, ys, aX, aY, active,
                                                        bitmaps, 10, MAXSEG, 1);
    k_scan_g<<<BB, 256, 0, stream>>>(bitmaps, proceed, ver, total, active, 10, MAXSEG, 0);

    k_accum2<<<BB * 4, 1024, 0, stream>>>(xs, ys, aX, aY, proceed, out);
}

// Round 6
// 85.280 us; speedup vs baseline: 1.9805x; 1.2046x over previous
//
#include <hip/hip_runtime.h>
#include <cstdint>
#include <cstddef>

#define BB 16
#define NTOT 1048576
#define SS 32
#define SEG 32768
#define DIM 256
#define VW 512        // verifier bitmap words (16384 bits)
#define PH 8          // partial blocks per (b,seg) histogram

// ---------------- workspace layout (bytes), sizes derived explicitly ----------
// histX : BB*SS*256*4 = 524,288      [0, 524288)
// histY : 524,288                    [524288, 1048576)   dead after k_shifts
// BM0   : 16*8segs*4parts*512*4 = 1,048,576  [1048576, 2097152) dead after scan0
// BM1   : 16*22segs*2parts*512*4 = 1,441,792 [0, 1441792) aliases dead hist+BM0
#define OFF_HX   0u
#define OFF_HY   524288u
#define OFF_BM0  1048576u
#define OFF_BM1  0u
#define OFF_AX   2097152u            // BB*SS*4 = 2048
#define OFF_AY   2099200u            // 2048
#define OFF_PR   2101248u            // 2048
#define OFF_ACT  2103296u            // 1024
#define OFF_TOT  2104320u            // 1024
#define OFF_VER  2105344u            // BB*VW*4 = 32768 -> end 2,138,112 (~2.14 MB)

__device__ __forceinline__ int clamp255(int v) {
    return v < 0 ? 0 : (v > 255 ? 255 : v);
}

// ---------------- K1: partial histograms, merged via global atomics ------------
// grid = BB*SS*PH; block (b,s,p) histograms elements [p*4096,(p+1)*4096).
// LDS-atomic-pipe bound (~12cy/wave-atomic, structural floor for random scatter).
__global__ __launch_bounds__(256) void k_hist(const int* __restrict__ xs,
                                              const int* __restrict__ ys,
                                              uint32_t* __restrict__ histX,
                                              uint32_t* __restrict__ histY) {
    int blk = blockIdx.x;
    int p = blk & (PH - 1);
    int s = (blk >> 3) & 31;
    int b = blk >> 8;
    __shared__ uint32_t hx[256];
    __shared__ uint32_t hy[256];
    int t = threadIdx.x;
    hx[t] = 0u; hy[t] = 0u;
    __syncthreads();
    size_t base = (size_t)b * NTOT + (size_t)s * SEG + (size_t)p * 4096;
    const int4* x4 = (const int4*)(xs + base);
    const int4* y4 = (const int4*)(ys + base);
#pragma unroll
    for (int i = 0; i < 4; ++i) {
        int4 xv = x4[i * 256 + t];
        int4 yv = y4[i * 256 + t];
        atomicAdd(&hx[xv.x], 1u); atomicAdd(&hy[yv.x], 1u);
        atomicAdd(&hx[xv.y], 1u); atomicAdd(&hy[yv.y], 1u);
        atomicAdd(&hx[xv.z], 1u); atomicAdd(&hy[yv.z], 1u);
        atomicAdd(&hx[xv.w], 1u); atomicAdd(&hy[yv.w], 1u);
    }
    __syncthreads();
    atomicAdd(&histX[(size_t)(b * SS + s) * 256 + t], hx[t]);
    atomicAdd(&histY[(size_t)(b * SS + s) * 256 + t], hy[t]);
}

// ---------------- K2: wave-parallel stats -> clip -> blur -> centroid -> shifts
// 32 blocks (b,axis) x 256 thr (4 waves). One row / one centroid per wave,
// shfl-butterfly reductions, no tree syncthreads. Pooled std (mean=128 exact,
// divisor 8191 — faithful to reference). Clip folded into blur reads (exact).
__global__ __launch_bounds__(256) void k_shifts(const uint32_t* __restrict__ histX,
                                                const uint32_t* __restrict__ histY,
                                                const float* __restrict__ blurk,
                                                int* __restrict__ alignedX,
                                                int* __restrict__ alignedY) {
    int blk = blockIdx.x;          // 0..31 : b*2 + axis
    int b = blk >> 1, axis = blk & 1;
    const uint32_t* hist = (axis == 0 ? histX : histY) + (size_t)b * SS * DIM;
    int* out = (axis == 0 ? alignedX : alignedY) + b * SS;

    __shared__ float vals[SS][DIM];
    __shared__ double wsq[4];
    __shared__ float mrow[SS];
    int t = threadIdx.x;
    int w = t >> 6, lane = t & 63;
    int c0 = lane << 2;                       // 4 columns per lane

    // load rows (wave w: rows w, w+4, ...) + pooled sum of squared deviations
    double lsq = 0.0;
    for (int r = w; r < SS; r += 4) {
        uint4 u = *(const uint4*)(hist + r * DIM + c0);
        float v0 = (float)u.x, v1 = (float)u.y, v2 = (float)u.z, v3 = (float)u.w;
        vals[r][c0 + 0] = v0; vals[r][c0 + 1] = v1;
        vals[r][c0 + 2] = v2; vals[r][c0 + 3] = v3;
        double d0 = (double)v0 - 128.0, d1 = (double)v1 - 128.0;
        double d2 = (double)v2 - 128.0, d3 = (double)v3 - 128.0;
        lsq += d0 * d0 + d1 * d1 + d2 * d2 + d3 * d3;
    }
    for (int o = 32; o > 0; o >>= 1) lsq += __shfl_xor(lsq, o, 64);
    if (lane == 0) wsq[w] = lsq;
    __syncthreads();
    float s2 = (float)(wsq[0] + wsq[1] + wsq[2] + wsq[3]);   // exact integer
    float sd = sqrtf(s2 / 8191.0f);                          // ddof=1, pooled
    float thr = 128.0f + 3.0f * sd;

    float k00 = blurk[0], k01 = blurk[1], k02 = blurk[2];
    float k10 = blurk[3], k11 = blurk[4], k12 = blurk[5];
    float k20 = blurk[6], k21 = blurk[7], k22 = blurk[8];

#define V(r, c) fminf(vals[r][c], thr)
    // centroid rows (wave w: s = w, w+4, ...)
    for (int s = w; s < SS; s += 4) {
        double dot = 0.0;
#pragma unroll
        for (int j = 0; j < 4; ++j) {
            int c = c0 + j;
            int cm = c - 1, cp = c + 1;
            bool cml = (cm >= 0), cpl = (cp < DIM);
            float bsum = 0.0f;
            if (s - 1 >= 0) {
                if (cml) bsum += k00 * V(s - 1, cm);
                bsum += k01 * V(s - 1, c);
                if (cpl) bsum += k02 * V(s - 1, cp);
            }
            if (cml) bsum += k10 * V(s, cm);
            bsum += k11 * V(s, c);
            if (cpl) bsum += k12 * V(s, cp);
            if (s + 1 < SS) {
                if (cml) bsum += k20 * V(s + 1, cm);
                bsum += k21 * V(s + 1, c);
                if (cpl) bsum += k22 * V(s + 1, cp);
            }
            dot += (double)bsum * (double)c;
        }
        for (int o = 32; o > 0; o >>= 1) dot += __shfl_xor(dot, o, 64);
        if (lane == 0) mrow[s] = (float)(dot / 32768.0);
    }
#undef V
    __syncthreads();

    if (t < SS) {
        float start = mrow[2];                    // START = 2
        float a = mrow[t] - start;
        float c = 128.0f - start;                 // dimlen//2 - start
        out[t] = (int)rintf(a - c);               // round half-to-even
    }
}

// ---------------- K3: partial verifier bitmaps for a segment group -------------
// grid = BB * nseg * parts; each partial block writes its own VW-word bitmap
// (no atomics to global, no zeroing — all words written unconditionally).
__global__ __launch_bounds__(256) void k_bitmap_g(const int* __restrict__ xs,
                                                  const int* __restrict__ ys,
                                                  const int* __restrict__ aX,
                                                  const int* __restrict__ aY,
                                                  const int* __restrict__ active,
                                                  uint32_t* __restrict__ bmp,
                                                  int first_seg, int nseg,
                                                  int parts, int check_active) {
    int blk = blockIdx.x;
    int p = blk % parts;
    int sl = (blk / parts) % nseg;
    int b = blk / (parts * nseg);
    if (check_active && !active[b]) return;
    int s = first_seg + sl;
    int shx = aX[b * SS + s];
    int shy = aY[b * SS + s];
    __shared__ uint32_t bm[VW];
    int t = threadIdx.x;
    bm[t] = 0u; bm[t + 256] = 0u;
    __syncthreads();
    size_t base = (size_t)b * NTOT + (size_t)s * SEG + (size_t)p * (SEG / parts);
    const int4* x4 = (const int4*)(xs + base);
    const int4* y4 = (const int4*)(ys + base);
    int iters = SEG / (parts * 1024);
    for (int i = 0; i < iters; ++i) {
        int4 xv = x4[i * 256 + t];
        int4 yv = y4[i * 256 + t];
#define DOV(xc, yc) { int xf = clamp255((xc) - shx); int yf = clamp255((yc) - shy); \
                      int iv = (xf >> 1) + ((yf >> 1) << 7); \
                      atomicOr(&bm[iv >> 5], 1u << (iv & 31)); }
        DOV(xv.x, yv.x) DOV(xv.y, yv.y) DOV(xv.z, yv.z) DOV(xv.w, yv.w)
#undef DOV
    }
    __syncthreads();
    uint32_t* outp = bmp + ((size_t)(b * nseg + sl) * parts + p) * VW;
    outp[t] = bm[t];
    outp[t + 256] = bm[t + 256];
}

// ---------------- K4: sequential verifier scan over one group ------------------
__global__ __launch_bounds__(256) void k_scan_g(const uint32_t* __restrict__ bmp,
                                                int* __restrict__ proceed,
                                                uint32_t* __restrict__ ver_state,
                                                int* __restrict__ total_state,
                                                int* __restrict__ active_state,
                                                int first_seg, int nseg,
                                                int parts, int do_init) {
    int b = blockIdx.x;                   // 0..15
    int t = threadIdx.x;
    __shared__ uint32_t ver[VW];
    __shared__ int wred[4];
    __shared__ int sh_flag;
    __shared__ int sh_total;

    // default proceed=0 for this group's segments
    for (int i = t; i < nseg; i += 256) proceed[b * SS + first_seg + i] = 0;

    int active = do_init ? 1 : active_state[b];
    if (!active) {
        if (t == 0) active_state[b] = 0;
        return;
    }

    const uint32_t* base = bmp + (size_t)b * nseg * parts * VW;
    int wid = t >> 6, lane = t & 63;
    int start_local;

    if (do_init) {
        uint32_t w0 = 0, w1 = 0;
        for (int p = 0; p < parts; ++p) {
            w0 |= base[(size_t)p * VW + t];
            w1 |= base[(size_t)p * VW + t + 256];
        }
        ver[t] = w0; ver[t + 256] = w1;
        int c = __popc(w0) + __popc(w1);
        for (int o = 32; o > 0; o >>= 1) c += __shfl_down(c, o, 64);
        if (lane == 0) wred[wid] = c;
        __syncthreads();
        if (t == 0) {
            sh_total = wred[0] + wred[1] + wred[2] + wred[3];
            proceed[b * SS + first_seg] = 1;   // START segment
        }
        start_local = 1;
    } else {
        ver[t] = ver_state[(size_t)b * VW + t];
        ver[t + 256] = ver_state[(size_t)b * VW + t + 256];
        if (t == 0) sh_total = total_state[b];
        start_local = 0;
    }
    __syncthreads();

    for (int sl = start_local; sl < nseg; ++sl) {
        uint32_t w0 = 0, w1 = 0;
        for (int p = 0; p < parts; ++p) {
            w0 |= base[(size_t)(sl * parts + p) * VW + t];
            w1 |= base[(size_t)(sl * parts + p) * VW + t + 256];
        }
        int c = __popc(w0 & ~ver[t]) + __popc(w1 & ~ver[t + 256]);
        for (int o = 32; o > 0; o >>= 1) c += __shfl_down(c, o, 64);
        if (lane == 0) wred[wid] = c;
        __syncthreads();
        if (t == 0) {
            int newly = wred[0] + wred[1] + wred[2] + wred[3];
            int total = sh_total + newly;
            float ratio = (float)newly / (float)total;
            int f = (ratio >= 0.01f) ? 1 : 0;
            sh_flag = f;
            if (f) {
                sh_total = total;
                proceed[b * SS + first_seg + sl] = 1;
            }
        }
        __syncthreads();
        if (!sh_flag) { active = 0; break; }
        ver[t] |= w0;
        ver[t + 256] |= w1;
        __syncthreads();
    }

    // save state for next group
    ver_state[(size_t)b * VW + t] = ver[t];
    ver_state[(size_t)b * VW + t + 256] = ver[t + 256];
    if (t == 0) {
        total_state[b] = sh_total;
        active_state[b] = active;
    }
}

// ---------------- K5: per-batch-half LDS accumulation --------------------------
// 2 blocks per batch; each owns y-rows [half*128, half*128+128). Packed u16
// counts in 64 KB LDS; plain coalesced stores cover all cells (no d_out memset).
__global__ __launch_bounds__(1024) void k_accum2(const int* __restrict__ xs,
                                                 const int* __restrict__ ys,
                                                 const int* __restrict__ aX,
                                                 const int* __restrict__ aY,
                                                 const int* __restrict__ proceed,
                                                 float* __restrict__ out) {
    int b = blockIdx.x >> 1, half = blockIdx.x & 1;   // 32 blocks
    __shared__ uint32_t acc[16384];                   // 32768 u16 cells (128x256)
    int t = threadIdx.x;
    for (int i = t; i < 16384; i += 1024) acc[i] = 0u;
    __syncthreads();
    int ybase = half << 7;
    for (int s = 2; s < SS; ++s) {
        if (!proceed[b * SS + s]) continue;
        int shx = aX[b * SS + s];
        int shy = aY[b * SS + s];
        const int4* x4 = (const int4*)(xs + (size_t)b * NTOT + (size_t)s * SEG);
        const int4* y4 = (const int4*)(ys + (size_t)b * NTOT + (size_t)s * SEG);
        for (int i = 0; i < 8; ++i) {
            int4 xv = x4[i * 1024 + t];
            int4 yv = y4[i * 1024 + t];
#define DOC(xc, yc) { int xf = clamp255((xc) - shx); int yf = clamp255((yc) - shy); \
                      if ((yf >> 7) == half) { \
                          int cell = xf + ((yf - ybase) << 8); \
                          atomicAdd(&acc[cell >> 1], 1u << ((cell & 1) << 4)); } }
            DOC(xv.x, yv.x) DOC(xv.y, yv.y) DOC(xv.z, yv.z) DOC(xv.w, yv.w)
#undef DOC
        }
    }
    __syncthreads();
    float2* ob = (float2*)(out + (size_t)b * 65536 + ((size_t)half << 15));
    for (int i = t; i < 16384; i += 1024) {
        uint32_t w = acc[i];
        ob[i] = make_float2((float)(w & 0xFFFFu), (float)(w >> 16));
    }
}

extern "C" void kernel_launch(void* const* d_in, const int* in_sizes, int n_in,
                              void* d_out, int out_size, void* d_ws, size_t ws_size,
                              hipStream_t stream) {
    const int* xs = (const int*)d_in[0];
    const int* ys = (const int*)d_in[1];
    const float* blurk = (const float*)d_in[2];
    float* out = (float*)d_out;

    uint8_t* ws = (uint8_t*)d_ws;
    uint32_t* histX = (uint32_t*)(ws + OFF_HX);
    uint32_t* histY = (uint32_t*)(ws + OFF_HY);
    int* aX = (int*)(ws + OFF_AX);
    int* aY = (int*)(ws + OFF_AY);
    int* proceed = (int*)(ws + OFF_PR);
    int* active = (int*)(ws + OFF_ACT);
    int* total = (int*)(ws + OFF_TOT);
    uint32_t* ver = (uint32_t*)(ws + OFF_VER);
    uint32_t* bm0 = (uint32_t*)(ws + OFF_BM0);
    uint32_t* bm1 = (uint32_t*)(ws + OFF_BM1);

    hipMemsetAsync(ws + OFF_HX, 0, 1048576, stream);   // zero hist X+Y (1 MB)

    k_hist<<<BB * SS * PH, 256, 0, stream>>>(xs, ys, histX, histY);
    k_shifts<<<BB * 2, 256, 0, stream>>>(histX, histY, blurk, aX, aY);

    // group 0: segments 2..9, 4 partials (init; no active check)
    k_bitmap_g<<<BB * 8 * 4, 256, 0, stream>>>(xs, ys, aX, aY, active,
                                               bm0, 2, 8, 4, 0);
    k_scan_g<<<BB, 256, 0, stream>>>(bm0, proceed, ver, total, active, 2, 8, 4, 1);

    // group 1: segments 10..31, 2 partials (active-gated; expected no-op).
    // bm1 aliases dead hist+bm0 regions.
    k_bitmap_g<<<BB * 22 * 2, 256, 0, stream>>>(xs, ys, aX, aY, active,
                                                bm1, 10, 22, 2, 1);
    k_scan_g<<<BB, 256, 0, stream>>>(bm1, proceed, ver, total, active, 10, 22, 2, 0);

    k_accum2<<<BB * 2, 1024, 0, stream>>>(xs, ys, aX, aY, proceed, out);
}